// Round 1
// baseline (127.407 us; speedup 1.0000x reference)
//
#include <hip/hip_runtime.h>
#include <hip/hip_bf16.h>

typedef __attribute__((ext_vector_type(8))) short short8;
typedef __attribute__((ext_vector_type(4))) float f32x4;

#define HID 64
#define FEATN 32

static __device__ __forceinline__ short f2bf(float f) {
    __hip_bfloat16 h = __float2bfloat16(f);
    return __builtin_bit_cast(short, h);
}

// One wave processes 256 contiguous samples as 16 tiles of 16.
// Tile: A = feats[16 samples][32 feats] (gathered, bf16), B = W1[32][64] as 4
// n-blocks -> 4x mfma_f32_16x16x32_bf16 with b1 folded into C-init.
// Layer 2 (64->4) on VALU: per-lane partials over n = 16j + (lane&15), then a
// 4-step reduce-scatter across the 16 lanes of each k-group so lane s ends
// owning output channel (r = s>>2 sample-in-quad, o = s&3). All-static reg
// indexing; lane-constant output routing.
__global__ __launch_bounds__(256, 4) void plen_fused(
    const float* __restrict__ pos,
    const float* __restrict__ table,
    const float* __restrict__ W1,
    const float* __restrict__ b1,
    const float* __restrict__ W2,
    const float* __restrict__ b2,
    float* __restrict__ out,
    int batch)
{
    const int lane = threadIdx.x & 63;
    const int row  = lane & 15;   // sample-in-tile for A; col for B/C
    const int g    = lane >> 4;   // k-group (A/B); sample-quad (C)

    // ---- preload weight fragments (tiny, L1/L2-cached after block 0) ----
    short8 w1f[4];          // B-frag per n-block j: W1[k=(g*8+i)][16j+row]
    float bias1[4];         // b1[16j+row]
    float w2f[4][4];        // W2[16j+row][o]
#pragma unroll
    for (int j = 0; j < 4; ++j) {
#pragma unroll
        for (int i = 0; i < 8; ++i)
            w1f[j][i] = f2bf(W1[(g * 8 + i) * HID + j * 16 + row]);
        bias1[j] = b1[j * 16 + row];
#pragma unroll
        for (int o = 0; o < 4; ++o)
            w2f[j][o] = W2[(j * 16 + row) * 4 + o];
    }

    // ---- lane-constant epilogue routing ----
    const int r_own = row >> 2;       // sample within quad
    const int o_own = row & 3;        // output channel
    const bool is_rgb = (o_own < 3);
    const float myb2 = b2[o_own];
    const int mult = is_rgb ? 3 : 1;
    const int coff = is_rgb ? ((4 * g + r_own) * 3 + o_own)
                            : (batch * 3 + 4 * g + r_own);

    const int wave_id = blockIdx.x * 4 + (threadIdx.x >> 6);
    const int chunk = wave_id * 256;

    for (int t = 0; t < 16; ++t) {
        const int base = chunk + t * 16;

        // voxel index for sample base+row (4x redundant across g, HW-dedup'd)
        const float* pp = pos + (size_t)(base + row) * 3;
        const float px = pp[0], py = pp[1], pz = pp[2];
        int ix = (int)(px * 128.0f);
        int iy = (int)(py * 128.0f);
        int iz = (int)(pz * 128.0f);
        ix = min(127, max(0, ix));
        iy = min(127, max(0, iy));
        iz = min(127, max(0, iz));
        const unsigned flat = ((unsigned)ix << 14) | ((unsigned)iy << 7) | (unsigned)iz;

        // gather 8 contiguous feats: A-frag k = g*8 + {0..7}
        const float* rp = table + (size_t)flat * FEATN + g * 8;
        const f32x4 f0 = *(const f32x4*)(rp);
        const f32x4 f1 = *(const f32x4*)(rp + 4);
        short8 afrag;
        afrag[0] = f2bf(f0[0]); afrag[1] = f2bf(f0[1]);
        afrag[2] = f2bf(f0[2]); afrag[3] = f2bf(f0[3]);
        afrag[4] = f2bf(f1[0]); afrag[5] = f2bf(f1[1]);
        afrag[6] = f2bf(f1[2]); afrag[7] = f2bf(f1[3]);

        // layer 1 (MFMA) + ReLU + layer-2 partials
        // C layout: lane holds h[m = 4g + r][n = 16j + row]
        float p[16];  // p[r*4+o], static indices only
#pragma unroll
        for (int j = 0; j < 4; ++j) {
            const f32x4 cinit = { bias1[j], bias1[j], bias1[j], bias1[j] };
            const f32x4 acc =
                __builtin_amdgcn_mfma_f32_16x16x32_bf16(afrag, w1f[j], cinit, 0, 0, 0);
#pragma unroll
            for (int r = 0; r < 4; ++r) {
                const float h = fmaxf(acc[r], 0.0f);
                if (j == 0) {
#pragma unroll
                    for (int o = 0; o < 4; ++o) p[r * 4 + o] = h * w2f[0][o];
                } else {
#pragma unroll
                    for (int o = 0; o < 4; ++o) p[r * 4 + o] = fmaf(h, w2f[j][o], p[r * 4 + o]);
                }
            }
        }

        // reduce-scatter across 16 lanes (same g): lane s ends with pair q = s
        float v8[8];
#pragma unroll
        for (int j = 0; j < 8; ++j) {
            const float a0 = p[2 * j], b0 = p[2 * j + 1];
            const float keep = (row & 1) ? b0 : a0;
            const float give = (row & 1) ? a0 : b0;
            v8[j] = keep + __shfl_xor(give, 1, 64);
        }
        float v4[4];
#pragma unroll
        for (int j = 0; j < 4; ++j) {
            const float a0 = v8[2 * j], b0 = v8[2 * j + 1];
            const float keep = (row & 2) ? b0 : a0;
            const float give = (row & 2) ? a0 : b0;
            v4[j] = keep + __shfl_xor(give, 2, 64);
        }
        float v2[2];
#pragma unroll
        for (int j = 0; j < 2; ++j) {
            const float a0 = v4[2 * j], b0 = v4[2 * j + 1];
            const float keep = (row & 4) ? b0 : a0;
            const float give = (row & 4) ? a0 : b0;
            v2[j] = keep + __shfl_xor(give, 4, 64);
        }
        {
            const float a0 = v2[0], b0 = v2[1];
            const float keep = (row & 8) ? b0 : a0;
            const float give = (row & 8) ? a0 : b0;
            const float v = keep + __shfl_xor(give, 8, 64) + myb2;

            float resv;
            if (is_rgb) {
                resv = __builtin_amdgcn_rcpf(1.0f + __expf(-v));        // sigmoid
            } else {
                resv = fmaxf(v, 0.0f) + __logf(1.0f + __expf(-fabsf(v))); // softplus
            }
            __builtin_nontemporal_store(resv, out + coff + base * mult);
        }
    }
}

extern "C" void kernel_launch(void* const* d_in, const int* in_sizes, int n_in,
                              void* d_out, int out_size, void* d_ws, size_t ws_size,
                              hipStream_t stream) {
    const float* pos   = (const float*)d_in[0];
    const float* table = (const float*)d_in[1];
    const float* W1    = (const float*)d_in[2];
    const float* b1    = (const float*)d_in[3];
    const float* W2    = (const float*)d_in[4];
    const float* b2    = (const float*)d_in[5];
    float* out = (float*)d_out;

    const int batch  = in_sizes[0] / 3;       // 4,194,304
    const int blocks = batch / 1024;          // 4 waves/block x 256 samples/wave
    hipLaunchKernelGGL(plen_fused, dim3(blocks), dim3(256), 0, stream,
                       pos, table, W1, b1, W2, b2, out, batch);
}

// Round 4
// 118.982 us; speedup vs baseline: 1.0708x; 1.0708x over previous
//
#include <hip/hip_runtime.h>
#include <hip/hip_bf16.h>

typedef __attribute__((ext_vector_type(8))) short bs8;
typedef __attribute__((ext_vector_type(4))) short bs4;
typedef __attribute__((ext_vector_type(4))) float f32x4;

#define HID 64
#define FEATN 32
#define NT 16   // tiles of 16 samples per wave

static __device__ __forceinline__ short f2bf(float f) {
    __hip_bfloat16 h = __float2bfloat16(f);
    return __builtin_bit_cast(short, h);
}

// Device pass: gfx950 has v_mfma_f32_16x16x16_bf16 via the gfx90a-era
// "_1k" builtin (signature verified by round-2 diagnostics: v4i16 operands).
// Host pass lacks amdgcn builtins -> no-op (kernel body never runs on host).
#if defined(__HIP_DEVICE_COMPILE__)
#define MFMA16(a, b, c) __builtin_amdgcn_mfma_f32_16x16x16bf16_1k(a, b, c, 0, 0, 0)
#else
#define MFMA16(a, b, c) (c)
#endif

// Layer 1 (transposed): h^T[hid][s] = W1^T x feats^T via 4x mfma_f32_16x16x32_bf16.
//   A = W1 chunk j (lane holds W1[8g+i][16j+row]), B = gathered feats
//   (lane row gathers its sample, k = 8g+i). C-layout: lane holds
//   h[16j+4g+r][sample=row] -- which IS the B-fragment of a 16x16x16 MFMA.
// Layer 2: out^T[o][s] = W2^T x h via 4 chained mfma_16x16x16_bf16,
//   A = W2^T chunk (static, rows o>=4 zeroed), b2 folded into C-init.
//   Result lands on g==0 lanes: oacc[r] = out[sample=row][channel=r].
__global__ __launch_bounds__(256, 4) void plen_fused(
    const float* __restrict__ pos,
    const float* __restrict__ table,
    const float* __restrict__ W1,
    const float* __restrict__ b1,
    const float* __restrict__ W2,
    const float* __restrict__ b2,
    float* __restrict__ out,
    int batch)
{
    const int lane = threadIdx.x & 63;
    const int row  = lane & 15;
    const int g    = lane >> 4;

    // ---- static weight fragments ----
    bs8   w1f[4];       // A-frag of layer 1, chunk j
    f32x4 bias1v[4];    // C-init: b1[16j + 4g + r]
    bs4   w2tf[4];      // A-frag of layer 2: W2^T[row][16j+4g+i], row<4 else 0
#pragma unroll
    for (int j = 0; j < 4; ++j) {
#pragma unroll
        for (int i = 0; i < 8; ++i)
            w1f[j][i] = f2bf(W1[(g * 8 + i) * HID + j * 16 + row]);
        bias1v[j] = *(const f32x4*)(b1 + j * 16 + g * 4);
#pragma unroll
        for (int i = 0; i < 4; ++i)
            w2tf[j][i] = (row < 4) ? f2bf(W2[(j * 16 + g * 4 + i) * 4 + row]) : (short)0;
    }
    f32x4 oinit;
    if (g == 0) oinit = *(const f32x4*)b2;
    else        oinit = (f32x4){0.f, 0.f, 0.f, 0.f};

    const int wave_id = blockIdx.x * 4 + (threadIdx.x >> 6);
    const int chunk   = wave_id * (NT * 16);
    const size_t dns_base = (size_t)batch * 3;

    auto loadpos = [&](int t, float& x, float& y, float& z) {
        const int tt = t < NT ? t : NT - 1;          // clamp redundant prefetch
        const float* pp = pos + (size_t)(chunk + tt * 16 + row) * 3;
        x = pp[0]; y = pp[1]; z = pp[2];
    };
    auto issue_gather = [&](float x, float y, float z, f32x4& A, f32x4& B) {
        const unsigned ix = (unsigned)(int)(x * 128.0f);
        const unsigned iy = (unsigned)(int)(y * 128.0f);
        const unsigned iz = (unsigned)(int)(z * 128.0f);
        const unsigned flat = (ix << 14) | (iy << 7) | iz;
        const float* rp = table + (size_t)flat * FEATN + g * 8;
        A = *(const f32x4*)rp;
        B = *(const f32x4*)(rp + 4);
    };
    auto compute = [&](int sbase, f32x4 f0, f32x4 f1) {
        bs8 af;
        af[0] = f2bf(f0[0]); af[1] = f2bf(f0[1]);
        af[2] = f2bf(f0[2]); af[3] = f2bf(f0[3]);
        af[4] = f2bf(f1[0]); af[5] = f2bf(f1[1]);
        af[6] = f2bf(f1[2]); af[7] = f2bf(f1[3]);

        f32x4 acc[4];
#pragma unroll
        for (int j = 0; j < 4; ++j)
            acc[j] = __builtin_amdgcn_mfma_f32_16x16x32_bf16(w1f[j], af, bias1v[j], 0, 0, 0);

        f32x4 oacc = oinit;
#pragma unroll
        for (int j = 0; j < 4; ++j) {
            bs4 pf;
            pf[0] = f2bf(fmaxf(acc[j][0], 0.0f));
            pf[1] = f2bf(fmaxf(acc[j][1], 0.0f));
            pf[2] = f2bf(fmaxf(acc[j][2], 0.0f));
            pf[3] = f2bf(fmaxf(acc[j][3], 0.0f));
            oacc = MFMA16(w2tf[j], pf, oacc);
        }

        const float r0 = __builtin_amdgcn_rcpf(1.0f + __expf(-oacc[0]));
        const float r1 = __builtin_amdgcn_rcpf(1.0f + __expf(-oacc[1]));
        const float r2 = __builtin_amdgcn_rcpf(1.0f + __expf(-oacc[2]));
        const float dv = oacc[3];
        const float dn = fmaxf(dv, 0.0f) + __logf(1.0f + __expf(-fabsf(dv)));

        if (g == 0) {
            const int s = sbase + row;
            float* rp = out + (size_t)s * 3;
            __builtin_nontemporal_store(r0, rp);
            __builtin_nontemporal_store(r1, rp + 1);
            __builtin_nontemporal_store(r2, rp + 2);
            __builtin_nontemporal_store(dn, out + dns_base + s);
        }
    };

    // ---- 3-stage pipeline: pos(t+2) || gather(t+1) || compute(t) ----
    float pxA, pyA, pzA, pxB, pyB, pzB;
    f32x4 gA0, gA1, gB0, gB1;
    loadpos(0, pxA, pyA, pzA);
    loadpos(1, pxB, pyB, pzB);
    issue_gather(pxA, pyA, pzA, gA0, gA1);

    for (int t = 0; t < NT; t += 2) {
        loadpos(t + 2, pxA, pyA, pzA);
        issue_gather(pxB, pyB, pzB, gB0, gB1);
        compute(chunk + t * 16, gA0, gA1);

        loadpos(t + 3, pxB, pyB, pzB);
        issue_gather(pxA, pyA, pzA, gA0, gA1);
        compute(chunk + (t + 1) * 16, gB0, gB1);
    }
}

extern "C" void kernel_launch(void* const* d_in, const int* in_sizes, int n_in,
                              void* d_out, int out_size, void* d_ws, size_t ws_size,
                              hipStream_t stream) {
    const float* pos   = (const float*)d_in[0];
    const float* table = (const float*)d_in[1];
    const float* W1    = (const float*)d_in[2];
    const float* b1    = (const float*)d_in[3];
    const float* W2    = (const float*)d_in[4];
    const float* b2    = (const float*)d_in[5];
    float* out = (float*)d_out;

    const int batch  = in_sizes[0] / 3;            // 4,194,304
    const int blocks = batch / (4 * NT * 16);      // 4096
    hipLaunchKernelGGL(plen_fused, dim3(blocks), dim3(256), 0, stream,
                       pos, table, W1, b1, W2, b2, out, batch);
}